// Round 1
// baseline (7560.239 us; speedup 1.0000x reference)
//
#include <hip/hip_runtime.h>
#include <hip/hip_bf16.h>
#include <stdint.h>

#define N_NODES 100000
#define N_EDGES 300000
#define HID 256

typedef unsigned short u16;
typedef unsigned int u32;

__device__ __forceinline__ float bf2f(u16 u) {
    union { u32 i; float f; } c; c.i = ((u32)u) << 16; return c.f;
}
__device__ __forceinline__ u16 f2bf(float f) {
    union { float f; u32 i; } c; c.f = f;
    u32 x = c.i;
    u32 r = (x + 0x7fffu + ((x >> 16) & 1u)) >> 16;  // round-nearest-even
    return (u16)r;
}
__device__ __forceinline__ u32 pk2(float lo, float hi) {
    return (u32)f2bf(lo) | ((u32)f2bf(hi) << 16);
}
__device__ __forceinline__ void unpack8(uint4 u, float* f) {
    f[0] = bf2f(u.x & 0xffffu); f[1] = bf2f(u.x >> 16);
    f[2] = bf2f(u.y & 0xffffu); f[3] = bf2f(u.y >> 16);
    f[4] = bf2f(u.z & 0xffffu); f[5] = bf2f(u.z >> 16);
    f[6] = bf2f(u.w & 0xffffu); f[7] = bf2f(u.w >> 16);
}

// ---------------- degree count / reciprocal ----------------
__global__ void cnt_k(const int* __restrict__ dst, float* __restrict__ cnt) {
    int e = blockIdx.x * blockDim.x + threadIdx.x;
    if (e < N_EDGES) atomicAdd(&cnt[dst[e]], 1.0f);
}
__global__ void inv_k(float* __restrict__ cnt) {
    int i = blockIdx.x * blockDim.x + threadIdx.x;
    if (i < N_NODES) cnt[i] = 1.0f / fmaxf(cnt[i], 1.0f);
}

// ---------------- edge-parallel mean-aggregation (sum part) ----------------
// 32 threads per edge, 8 channels each; bf16 gather, f32 atomic scatter.
__global__ void agg_k(const u16* __restrict__ x, const int* __restrict__ src,
                      const int* __restrict__ dst, float* __restrict__ agg) {
    int t = blockIdx.x * blockDim.x + threadIdx.x;
    int e = t >> 5;
    if (e >= N_EDGES) return;
    int q = t & 31;
    int s = src[e], d = dst[e];
    uint4 u = *(const uint4*)(x + (size_t)s * HID + q * 8);
    float f[8];
    unpack8(u, f);
    float* ap = agg + (size_t)d * HID + q * 8;
    #pragma unroll
    for (int j = 0; j < 8; ++j) atomicAdd(ap + j, f[j]);
}

// ---------------- fused GEMM ----------------
// out[r,c] = sum_{k<K1} (A1[r,k]*scale[r]) * B1[k,c]  +  sum_{k<K2} A2bf[r,k] * B2[k,c]
// MODE 0: v=acc+bias; outb2=bf16(v) (pre-relu), outb=bf16(relu(v)).   (CPT=8)
// MODE 1: v=relu(acc+bias)+0.2*inp;  outb=bf16(v).                    (CPT=8)
// MODE 2: v=acc+bias; outf=v (stride 64).                             (CPT=4)
template<int KC1, int KC2, int MODE, int CPT>
__launch_bounds__(256)
__global__ void gemm_k(const float* __restrict__ A1, int lda1,
                       const float* __restrict__ rowscale,
                       const u16* __restrict__ A2,
                       const float* __restrict__ B1,
                       const float* __restrict__ B2,
                       int ldb,
                       const float* __restrict__ bias,
                       const u16* __restrict__ inp,
                       u16* __restrict__ outb,
                       u16* __restrict__ outb2,
                       float* __restrict__ outf) {
    constexpr int BN = CPT * 16;
    __shared__ float As[128][33];
    __shared__ float Bs[32][BN + 8];

    const int tid = threadIdx.x;
    const int r0 = blockIdx.x * 128;
    const int c0 = blockIdx.y * BN;
    const int tc = tid & 15, tr = tid >> 4;

    float acc[8][CPT];
    #pragma unroll
    for (int i = 0; i < 8; ++i)
        #pragma unroll
        for (int j = 0; j < CPT; ++j) acc[i][j] = 0.0f;

    constexpr int KC = KC1 + KC2;
    for (int kc = 0; kc < KC; ++kc) {
        // ---- stage B tile [32 x BN] ----
        {
            const float* B = (kc < KC1) ? B1 : B2;
            int k0 = ((kc < KC1) ? kc : (kc - KC1)) * 32;
            int k = tid >> 3;
            int cl = (tid & 7) * (BN / 8);
            const float* bp = B + (size_t)(k0 + k) * ldb + c0 + cl;
            #pragma unroll
            for (int q = 0; q < BN / 32; ++q) {
                float4 v = *(const float4*)(bp + 4 * q);
                *(float4*)&Bs[k][cl + 4 * q] = v;
            }
        }
        // ---- stage A tile [128 x 32] ----
        if (kc < KC1) {
            int k0 = kc * 32;
            int cl = (tid & 7) * 4;
            #pragma unroll
            for (int rr = 0; rr < 4; ++rr) {
                int rl = rr * 32 + (tid >> 3);
                int gr = r0 + rl;
                float4 v = make_float4(0.f, 0.f, 0.f, 0.f);
                if (gr < N_NODES) {
                    v = *(const float4*)(A1 + (size_t)gr * lda1 + k0 + cl);
                    if (rowscale) {
                        float s = rowscale[gr];
                        v.x *= s; v.y *= s; v.z *= s; v.w *= s;
                    }
                }
                As[rl][cl + 0] = v.x; As[rl][cl + 1] = v.y;
                As[rl][cl + 2] = v.z; As[rl][cl + 3] = v.w;
            }
        } else {
            int k0 = (kc - KC1) * 32;
            int cl = (tid & 3) * 8;
            #pragma unroll
            for (int rr = 0; rr < 2; ++rr) {
                int rl = rr * 64 + (tid >> 2);
                int gr = r0 + rl;
                float f[8];
                if (gr < N_NODES) {
                    uint4 u = *(const uint4*)(A2 + (size_t)gr * HID + k0 + cl);
                    unpack8(u, f);
                } else {
                    #pragma unroll
                    for (int j = 0; j < 8; ++j) f[j] = 0.f;
                }
                #pragma unroll
                for (int j = 0; j < 8; ++j) As[rl][cl + j] = f[j];
            }
        }
        __syncthreads();

        // ---- compute ----
        #pragma unroll
        for (int k = 0; k < 32; ++k) {
            float a[8];
            #pragma unroll
            for (int i = 0; i < 8; ++i) a[i] = As[tr * 8 + i][k];
            float b[CPT];
            #pragma unroll
            for (int q = 0; q < CPT / 4; ++q) {
                float4 t = *(const float4*)&Bs[k][tc * CPT + 4 * q];
                b[4 * q + 0] = t.x; b[4 * q + 1] = t.y;
                b[4 * q + 2] = t.z; b[4 * q + 3] = t.w;
            }
            #pragma unroll
            for (int i = 0; i < 8; ++i)
                #pragma unroll
                for (int j = 0; j < CPT; ++j)
                    acc[i][j] = fmaf(a[i], b[j], acc[i][j]);
        }
        __syncthreads();
    }

    // ---- epilogue ----
    #pragma unroll
    for (int i = 0; i < 8; ++i) {
        int gr = r0 + tr * 8 + i;
        if (gr >= N_NODES) continue;
        float v[CPT];
        #pragma unroll
        for (int j = 0; j < CPT; ++j) v[j] = acc[i][j] + bias[c0 + tc * CPT + j];

        if constexpr (MODE == 0) {
            uint4 p, q;
            p.x = pk2(v[0], v[1]); p.y = pk2(v[2], v[3]);
            p.z = pk2(v[4], v[5]); p.w = pk2(v[6], v[7]);
            q.x = pk2(fmaxf(v[0], 0.f), fmaxf(v[1], 0.f));
            q.y = pk2(fmaxf(v[2], 0.f), fmaxf(v[3], 0.f));
            q.z = pk2(fmaxf(v[4], 0.f), fmaxf(v[5], 0.f));
            q.w = pk2(fmaxf(v[6], 0.f), fmaxf(v[7], 0.f));
            *(uint4*)(outb2 + (size_t)gr * HID + c0 + tc * 8) = p;
            *(uint4*)(outb + (size_t)gr * HID + c0 + tc * 8) = q;
        } else if constexpr (MODE == 1) {
            uint4 ip = *(const uint4*)(inp + (size_t)gr * HID + c0 + tc * 8);
            float f[8];
            unpack8(ip, f);
            #pragma unroll
            for (int j = 0; j < 8; ++j) v[j] = fmaxf(v[j], 0.f) + 0.2f * f[j];
            uint4 q;
            q.x = pk2(v[0], v[1]); q.y = pk2(v[2], v[3]);
            q.z = pk2(v[4], v[5]); q.w = pk2(v[6], v[7]);
            *(uint4*)(outb + (size_t)gr * HID + c0 + tc * 8) = q;
        } else {
            *(float4*)(outf + (size_t)gr * 64 + c0 + tc * 4) =
                make_float4(v[0], v[1], v[2], v[3]);
        }
    }
}

// ---------------- in-place log_softmax over 64 cols, one wave per row ----------------
__global__ void lsm_k(float* __restrict__ out) {
    int r = blockIdx.x * 4 + (threadIdx.x >> 6);
    int lane = threadIdx.x & 63;
    if (r >= N_NODES) return;
    float v = out[(size_t)r * 64 + lane];
    float m = v;
    #pragma unroll
    for (int off = 32; off; off >>= 1) m = fmaxf(m, __shfl_xor(m, off));
    float s = expf(v - m);
    #pragma unroll
    for (int off = 32; off; off >>= 1) s += __shfl_xor(s, off);
    out[(size_t)r * 64 + lane] = (v - m) - logf(s);
}

extern "C" void kernel_launch(void* const* d_in, const int* in_sizes, int n_in,
                              void* d_out, int out_size, void* d_ws, size_t ws_size,
                              hipStream_t stream) {
    const float* x    = (const float*)d_in[0];
    const int*   ei   = (const int*)d_in[1];
    const float* W_in = (const float*)d_in[2];
    const float* b_in = (const float*)d_in[3];
    const float* Wl1  = (const float*)d_in[4];
    const float* bl1  = (const float*)d_in[5];
    const float* Wr1  = (const float*)d_in[6];
    const float* Wl2  = (const float*)d_in[7];
    const float* bl2  = (const float*)d_in[8];
    const float* Wr2  = (const float*)d_in[9];
    const float* Wl3  = (const float*)d_in[10];
    const float* bl3  = (const float*)d_in[11];
    const float* Wr3  = (const float*)d_in[12];
    float* out = (float*)d_out;

    const int* esrc = ei;
    const int* edst = ei + N_EDGES;

    char* ws = (char*)d_ws;
    u16*   inp = (u16*)(ws + 0);                  // 100000*256*2 = 51,200,000
    u16*   xA  = (u16*)(ws + 51200000);           // 51,200,000
    u16*   xB  = (u16*)(ws + 102400000);          // 51,200,000
    float* agg = (float*)(ws + 153600000);        // 100000*256*4 = 102,400,000
    float* cnt = (float*)(ws + 256000000);        // 400,000

    const size_t aggBytes = (size_t)N_NODES * HID * 4;

    // degrees
    hipMemsetAsync(cnt, 0, (size_t)N_NODES * 4, stream);
    cnt_k<<<(N_EDGES + 255) / 256, 256, 0, stream>>>(edst, cnt);
    inv_k<<<(N_NODES + 255) / 256, 256, 0, stream>>>(cnt);

    dim3 blk(256);
    dim3 g2((N_NODES + 127) / 128, 2);
    dim3 g1((N_NODES + 127) / 128, 1);
    dim3 gagg((N_EDGES * 32) / 256);

    // input: H0 = x @ W_in + b_in ; inp = H0 (pre-relu), xA = relu(H0)
    gemm_k<4, 0, 0, 8><<<g2, blk, 0, stream>>>(x, 128, nullptr, nullptr,
                                               W_in, nullptr, 256, b_in,
                                               nullptr, xA, inp, nullptr);

    // ---- layer 1 ----
    hipMemsetAsync(agg, 0, aggBytes, stream);
    agg_k<<<gagg, blk, 0, stream>>>(xA, esrc, edst, agg);
    gemm_k<8, 8, 1, 8><<<g2, blk, 0, stream>>>(agg, 256, cnt, xA,
                                               Wl1, Wr1, 256, bl1,
                                               inp, xB, nullptr, nullptr);

    // ---- layer 2 ----
    hipMemsetAsync(agg, 0, aggBytes, stream);
    agg_k<<<gagg, blk, 0, stream>>>(xB, esrc, edst, agg);
    gemm_k<8, 8, 1, 8><<<g2, blk, 0, stream>>>(agg, 256, cnt, xB,
                                               Wl2, Wr2, 256, bl2,
                                               inp, xA, nullptr, nullptr);

    // ---- layer 3 ----
    hipMemsetAsync(agg, 0, aggBytes, stream);
    agg_k<<<gagg, blk, 0, stream>>>(xA, esrc, edst, agg);
    gemm_k<8, 8, 2, 4><<<g1, blk, 0, stream>>>(agg, 256, cnt, xA,
                                               Wl3, Wr3, 64, bl3,
                                               nullptr, nullptr, nullptr, out);

    // log_softmax in place
    lsm_k<<<N_NODES / 4, blk, 0, stream>>>(out);
}

// Round 2
// 1235.955 us; speedup vs baseline: 6.1169x; 6.1169x over previous
//
#include <hip/hip_runtime.h>
#include <hip/hip_bf16.h>
#include <stdint.h>

#define N_NODES 100000
#define N_EDGES 300000
#define HID 256
#define NB_SCAN 98   // ceil(100000/1024)

typedef unsigned short u16;
typedef unsigned int u32;

__device__ __forceinline__ float bf2f(u16 u) {
    union { u32 i; float f; } c; c.i = ((u32)u) << 16; return c.f;
}
__device__ __forceinline__ u16 f2bf(float f) {
    union { float f; u32 i; } c; c.f = f;
    u32 x = c.i;
    u32 r = (x + 0x7fffu + ((x >> 16) & 1u)) >> 16;  // round-nearest-even
    return (u16)r;
}
__device__ __forceinline__ u32 pk2(float lo, float hi) {
    return (u32)f2bf(lo) | ((u32)f2bf(hi) << 16);
}
__device__ __forceinline__ void unpack8(uint4 u, float* f) {
    f[0] = bf2f(u.x & 0xffffu); f[1] = bf2f(u.x >> 16);
    f[2] = bf2f(u.y & 0xffffu); f[3] = bf2f(u.y >> 16);
    f[4] = bf2f(u.z & 0xffffu); f[5] = bf2f(u.z >> 16);
    f[6] = bf2f(u.w & 0xffffu); f[7] = bf2f(u.w >> 16);
}

// ---------------- CSR build ----------------
__global__ void icnt_k(const int* __restrict__ dst, int* __restrict__ icnt) {
    int e = blockIdx.x * blockDim.x + threadIdx.x;
    if (e < N_EDGES) atomicAdd(&icnt[dst[e]], 1);
}

// 1024 elements per block, 256 threads x 4 elements
__global__ void scan1_k(const int* __restrict__ icnt, int* __restrict__ off,
                        int* __restrict__ bsum) {
    __shared__ int sh[256];
    int t = threadIdx.x;
    int base = blockIdx.x * 1024 + t * 4;
    int v[4];
    #pragma unroll
    for (int j = 0; j < 4; ++j) {
        int idx = base + j;
        v[j] = (idx < N_NODES) ? icnt[idx] : 0;
    }
    int s = v[0] + v[1] + v[2] + v[3];
    sh[t] = s;
    __syncthreads();
    #pragma unroll
    for (int d = 1; d < 256; d <<= 1) {
        int x = (t >= d) ? sh[t - d] : 0;
        __syncthreads();
        if (t >= d) sh[t] += x;
        __syncthreads();
    }
    int excl = sh[t] - s;
    #pragma unroll
    for (int j = 0; j < 4; ++j) {
        int idx = base + j;
        if (idx < N_NODES) off[idx] = excl;
        excl += v[j];
    }
    if (t == 255) bsum[blockIdx.x] = sh[255];
}

__global__ void scan2_k(int* __restrict__ bsum) {  // exclusive in-place, NB_SCAN elems
    __shared__ int sh[128];
    int t = threadIdx.x;
    int v = (t < NB_SCAN) ? bsum[t] : 0;
    sh[t] = v;
    __syncthreads();
    #pragma unroll
    for (int d = 1; d < 128; d <<= 1) {
        int x = (t >= d) ? sh[t - d] : 0;
        __syncthreads();
        if (t >= d) sh[t] += x;
        __syncthreads();
    }
    if (t < NB_SCAN) bsum[t] = sh[t] - v;
}

__global__ void scan3_k(int* __restrict__ off, int* __restrict__ pos,
                        const int* __restrict__ bsum) {
    int idx = blockIdx.x * blockDim.x + threadIdx.x;
    if (idx < N_NODES) {
        int o = off[idx] + bsum[idx >> 10];
        off[idx] = o;
        pos[idx] = o;
    }
}

__global__ void scat_k(const int* __restrict__ src, const int* __restrict__ dst,
                       int* __restrict__ pos, int* __restrict__ csrc) {
    int e = blockIdx.x * blockDim.x + threadIdx.x;
    if (e < N_EDGES) {
        int slot = atomicAdd(&pos[dst[e]], 1);
        csrc[slot] = src[e];
    }
}

// ---------------- CSR mean aggregation: one wave per node ----------------
// after scat_k, pos[i] == end of node i's bucket; off[i] == start.
__global__ void aggc_k(const u16* __restrict__ x, const int* __restrict__ off,
                       const int* __restrict__ pos, const int* __restrict__ csrc,
                       u16* __restrict__ mean) {
    int node = blockIdx.x * (blockDim.x >> 6) + (threadIdx.x >> 6);
    if (node >= N_NODES) return;
    int lane = threadIdx.x & 63;
    int s = off[node], e = pos[node];
    float acc[4] = {0.f, 0.f, 0.f, 0.f};
    for (int i = s; i < e; ++i) {
        int sr = csrc[i];
        uint2 u = *(const uint2*)(x + (size_t)sr * HID + lane * 4);
        acc[0] += bf2f(u.x & 0xffffu); acc[1] += bf2f(u.x >> 16);
        acc[2] += bf2f(u.y & 0xffffu); acc[3] += bf2f(u.y >> 16);
    }
    float inv = 1.0f / fmaxf((float)(e - s), 1.0f);
    uint2 r;
    r.x = pk2(acc[0] * inv, acc[1] * inv);
    r.y = pk2(acc[2] * inv, acc[3] * inv);
    *(uint2*)(mean + (size_t)node * HID + lane * 4) = r;
}

// ---------------- fused GEMM ----------------
// acc = sum_{k<32*KC1} A1[r,k] * B1[k,c] + sum_{k<32*KC2} A2[r,k] * B2[k,c]
// A1 is fp32 (lda1) when A1F32, else bf16 with 256 cols. A2 is bf16, 256 cols.
// MODE 0: v=acc+bias; outb2=bf16(v) (pre-relu), outb=bf16(relu(v)).   (CPT=8)
// MODE 1: v=relu(acc+bias)+0.2*inp;  outb=bf16(v).                    (CPT=8)
// MODE 2: v=acc+bias; outf=v (stride 64).                             (CPT=4)
template<int KC1, int KC2, int MODE, int CPT, bool A1F32>
__launch_bounds__(256)
__global__ void gemm_k(const void* __restrict__ A1v, int lda1,
                       const u16* __restrict__ A2,
                       const float* __restrict__ B1,
                       const float* __restrict__ B2,
                       int ldb,
                       const float* __restrict__ bias,
                       const u16* __restrict__ inp,
                       u16* __restrict__ outb,
                       u16* __restrict__ outb2,
                       float* __restrict__ outf) {
    constexpr int BN = CPT * 16;
    __shared__ float As[128][33];
    __shared__ float Bs[32][BN + 8];

    const int tid = threadIdx.x;
    const int r0 = blockIdx.x * 128;
    const int c0 = blockIdx.y * BN;
    const int tc = tid & 15, tr = tid >> 4;

    float acc[8][CPT];
    #pragma unroll
    for (int i = 0; i < 8; ++i)
        #pragma unroll
        for (int j = 0; j < CPT; ++j) acc[i][j] = 0.0f;

    constexpr int KC = KC1 + KC2;
    for (int kc = 0; kc < KC; ++kc) {
        // ---- stage B tile [32 x BN] ----
        {
            const float* B = (kc < KC1) ? B1 : B2;
            int k0 = ((kc < KC1) ? kc : (kc - KC1)) * 32;
            int k = tid >> 3;
            int cl = (tid & 7) * (BN / 8);
            const float* bp = B + (size_t)(k0 + k) * ldb + c0 + cl;
            #pragma unroll
            for (int q = 0; q < BN / 32; ++q) {
                float4 v = *(const float4*)(bp + 4 * q);
                *(float4*)&Bs[k][cl + 4 * q] = v;
            }
        }
        // ---- stage A tile [128 x 32] ----
        if constexpr (A1F32) {
            const float* A1 = (const float*)A1v;
            int k0 = kc * 32;
            int cl = (tid & 7) * 4;
            #pragma unroll
            for (int rr = 0; rr < 4; ++rr) {
                int rl = rr * 32 + (tid >> 3);
                int gr = r0 + rl;
                float4 v = make_float4(0.f, 0.f, 0.f, 0.f);
                if (gr < N_NODES)
                    v = *(const float4*)(A1 + (size_t)gr * lda1 + k0 + cl);
                As[rl][cl + 0] = v.x; As[rl][cl + 1] = v.y;
                As[rl][cl + 2] = v.z; As[rl][cl + 3] = v.w;
            }
        } else {
            const u16* Ab = (kc < KC1) ? (const u16*)A1v : A2;
            int k0 = ((kc < KC1) ? kc : (kc - KC1)) * 32;
            int cl = (tid & 3) * 8;
            #pragma unroll
            for (int rr = 0; rr < 2; ++rr) {
                int rl = rr * 64 + (tid >> 2);
                int gr = r0 + rl;
                float f[8];
                if (gr < N_NODES) {
                    uint4 u = *(const uint4*)(Ab + (size_t)gr * HID + k0 + cl);
                    unpack8(u, f);
                } else {
                    #pragma unroll
                    for (int j = 0; j < 8; ++j) f[j] = 0.f;
                }
                #pragma unroll
                for (int j = 0; j < 8; ++j) As[rl][cl + j] = f[j];
            }
        }
        __syncthreads();

        // ---- compute ----
        #pragma unroll
        for (int k = 0; k < 32; ++k) {
            float a[8];
            #pragma unroll
            for (int i = 0; i < 8; ++i) a[i] = As[tr * 8 + i][k];
            float b[CPT];
            #pragma unroll
            for (int q = 0; q < CPT / 4; ++q) {
                float4 t = *(const float4*)&Bs[k][tc * CPT + 4 * q];
                b[4 * q + 0] = t.x; b[4 * q + 1] = t.y;
                b[4 * q + 2] = t.z; b[4 * q + 3] = t.w;
            }
            #pragma unroll
            for (int i = 0; i < 8; ++i)
                #pragma unroll
                for (int j = 0; j < CPT; ++j)
                    acc[i][j] = fmaf(a[i], b[j], acc[i][j]);
        }
        __syncthreads();
    }

    // ---- epilogue ----
    #pragma unroll
    for (int i = 0; i < 8; ++i) {
        int gr = r0 + tr * 8 + i;
        if (gr >= N_NODES) continue;
        float v[CPT];
        #pragma unroll
        for (int j = 0; j < CPT; ++j) v[j] = acc[i][j] + bias[c0 + tc * CPT + j];

        if constexpr (MODE == 0) {
            uint4 p, q;
            p.x = pk2(v[0], v[1]); p.y = pk2(v[2], v[3]);
            p.z = pk2(v[4], v[5]); p.w = pk2(v[6], v[7]);
            q.x = pk2(fmaxf(v[0], 0.f), fmaxf(v[1], 0.f));
            q.y = pk2(fmaxf(v[2], 0.f), fmaxf(v[3], 0.f));
            q.z = pk2(fmaxf(v[4], 0.f), fmaxf(v[5], 0.f));
            q.w = pk2(fmaxf(v[6], 0.f), fmaxf(v[7], 0.f));
            *(uint4*)(outb2 + (size_t)gr * HID + c0 + tc * 8) = p;
            *(uint4*)(outb + (size_t)gr * HID + c0 + tc * 8) = q;
        } else if constexpr (MODE == 1) {
            uint4 ip = *(const uint4*)(inp + (size_t)gr * HID + c0 + tc * 8);
            float f[8];
            unpack8(ip, f);
            #pragma unroll
            for (int j = 0; j < 8; ++j) v[j] = fmaxf(v[j], 0.f) + 0.2f * f[j];
            uint4 q;
            q.x = pk2(v[0], v[1]); q.y = pk2(v[2], v[3]);
            q.z = pk2(v[4], v[5]); q.w = pk2(v[6], v[7]);
            *(uint4*)(outb + (size_t)gr * HID + c0 + tc * 8) = q;
        } else {
            *(float4*)(outf + (size_t)gr * 64 + c0 + tc * 4) =
                make_float4(v[0], v[1], v[2], v[3]);
        }
    }
}

// ---------------- in-place log_softmax over 64 cols, one wave per row ----------------
__global__ void lsm_k(float* __restrict__ out) {
    int r = blockIdx.x * 4 + (threadIdx.x >> 6);
    int lane = threadIdx.x & 63;
    if (r >= N_NODES) return;
    float v = out[(size_t)r * 64 + lane];
    float m = v;
    #pragma unroll
    for (int off = 32; off; off >>= 1) m = fmaxf(m, __shfl_xor(m, off));
    float s = expf(v - m);
    #pragma unroll
    for (int off = 32; off; off >>= 1) s += __shfl_xor(s, off);
    out[(size_t)r * 64 + lane] = (v - m) - logf(s);
}

extern "C" void kernel_launch(void* const* d_in, const int* in_sizes, int n_in,
                              void* d_out, int out_size, void* d_ws, size_t ws_size,
                              hipStream_t stream) {
    const float* x    = (const float*)d_in[0];
    const int*   ei   = (const int*)d_in[1];
    const float* W_in = (const float*)d_in[2];
    const float* b_in = (const float*)d_in[3];
    const float* Wl1  = (const float*)d_in[4];
    const float* bl1  = (const float*)d_in[5];
    const float* Wr1  = (const float*)d_in[6];
    const float* Wl2  = (const float*)d_in[7];
    const float* bl2  = (const float*)d_in[8];
    const float* Wr2  = (const float*)d_in[9];
    const float* Wl3  = (const float*)d_in[10];
    const float* bl3  = (const float*)d_in[11];
    const float* Wr3  = (const float*)d_in[12];
    float* out = (float*)d_out;

    const int* esrc = ei;
    const int* edst = ei + N_EDGES;

    char* ws = (char*)d_ws;
    u16* inp   = (u16*)(ws + 0);            // 51,200,000
    u16* xA    = (u16*)(ws + 51200000);     // 51,200,000
    u16* xB    = (u16*)(ws + 102400000);    // 51,200,000
    u16* mean  = (u16*)(ws + 153600000);    // 51,200,000
    int* icnt  = (int*)(ws + 204800000);    // 400,000
    int* coff  = (int*)(ws + 205200000);    // 400,000
    int* cpos  = (int*)(ws + 205600000);    // 400,000
    int* csrc  = (int*)(ws + 206000000);    // 1,200,000
    int* bsum  = (int*)(ws + 207200000);    // 512

    dim3 blk(256);
    dim3 g2((N_NODES + 127) / 128, 2);
    dim3 g1((N_NODES + 127) / 128, 1);
    dim3 gE((N_EDGES + 255) / 256);
    dim3 gN((N_NODES + 255) / 256);
    dim3 gAgg((N_NODES + 3) / 4);

    // ---- CSR build ----
    hipMemsetAsync(icnt, 0, (size_t)N_NODES * 4, stream);
    icnt_k<<<gE, blk, 0, stream>>>(edst, icnt);
    scan1_k<<<NB_SCAN, blk, 0, stream>>>(icnt, coff, bsum);
    scan2_k<<<1, 128, 0, stream>>>(bsum);
    scan3_k<<<gN, blk, 0, stream>>>(coff, cpos, bsum);
    scat_k<<<gE, blk, 0, stream>>>(esrc, edst, cpos, csrc);

    // ---- input: H0 = x @ W_in + b_in ; inp = H0 (pre-relu), xA = relu(H0) ----
    gemm_k<4, 0, 0, 8, true><<<g2, blk, 0, stream>>>(x, 128, nullptr,
                                                     W_in, nullptr, 256, b_in,
                                                     nullptr, xA, inp, nullptr);

    // ---- layer 1 ----
    aggc_k<<<gAgg, blk, 0, stream>>>(xA, coff, cpos, csrc, mean);
    gemm_k<8, 8, 1, 8, false><<<g2, blk, 0, stream>>>(mean, 256, xA,
                                                      Wl1, Wr1, 256, bl1,
                                                      inp, xB, nullptr, nullptr);

    // ---- layer 2 ----
    aggc_k<<<gAgg, blk, 0, stream>>>(xB, coff, cpos, csrc, mean);
    gemm_k<8, 8, 1, 8, false><<<g2, blk, 0, stream>>>(mean, 256, xB,
                                                      Wl2, Wr2, 256, bl2,
                                                      inp, xA, nullptr, nullptr);

    // ---- layer 3 ----
    aggc_k<<<gAgg, blk, 0, stream>>>(xA, coff, cpos, csrc, mean);
    gemm_k<8, 8, 2, 4, false><<<g1, blk, 0, stream>>>(mean, 256, xA,
                                                      Wl3, Wr3, 64, bl3,
                                                      nullptr, nullptr, nullptr, out);

    // ---- log_softmax in place ----
    lsm_k<<<N_NODES / 4, blk, 0, stream>>>(out);
}

// Round 3
// 410.908 us; speedup vs baseline: 18.3989x; 3.0079x over previous
//
#include <hip/hip_runtime.h>
#include <hip/hip_bf16.h>
#include <stdint.h>

#define N_NODES 100000
#define N_EDGES 300000
#define HID 256
#define NB_SCAN 98   // ceil(100000/1024)

typedef unsigned short u16;
typedef unsigned int u32;
typedef __attribute__((ext_vector_type(8))) short short8;
typedef __attribute__((ext_vector_type(4))) float f32x4;

__device__ __forceinline__ float bf2f(u16 u) {
    union { u32 i; float f; } c; c.i = ((u32)u) << 16; return c.f;
}
__device__ __forceinline__ u16 f2bf(float f) {
    union { float f; u32 i; } c; c.f = f;
    u32 x = c.i;
    u32 r = (x + 0x7fffu + ((x >> 16) & 1u)) >> 16;  // round-nearest-even
    return (u16)r;
}
__device__ __forceinline__ u32 pk2(float lo, float hi) {
    return (u32)f2bf(lo) | ((u32)f2bf(hi) << 16);
}

// ---------------- CSR build ----------------
__global__ void icnt_k(const int* __restrict__ dst, int* __restrict__ icnt) {
    int e = blockIdx.x * blockDim.x + threadIdx.x;
    if (e < N_EDGES) atomicAdd(&icnt[dst[e]], 1);
}

__global__ void scan1_k(const int* __restrict__ icnt, int* __restrict__ off,
                        int* __restrict__ bsum) {
    __shared__ int sh[256];
    int t = threadIdx.x;
    int base = blockIdx.x * 1024 + t * 4;
    int v[4];
    #pragma unroll
    for (int j = 0; j < 4; ++j) {
        int idx = base + j;
        v[j] = (idx < N_NODES) ? icnt[idx] : 0;
    }
    int s = v[0] + v[1] + v[2] + v[3];
    sh[t] = s;
    __syncthreads();
    #pragma unroll
    for (int d = 1; d < 256; d <<= 1) {
        int x = (t >= d) ? sh[t - d] : 0;
        __syncthreads();
        if (t >= d) sh[t] += x;
        __syncthreads();
    }
    int excl = sh[t] - s;
    #pragma unroll
    for (int j = 0; j < 4; ++j) {
        int idx = base + j;
        if (idx < N_NODES) off[idx] = excl;
        excl += v[j];
    }
    if (t == 255) bsum[blockIdx.x] = sh[255];
}

__global__ void scan2_k(int* __restrict__ bsum) {
    __shared__ int sh[128];
    int t = threadIdx.x;
    int v = (t < NB_SCAN) ? bsum[t] : 0;
    sh[t] = v;
    __syncthreads();
    #pragma unroll
    for (int d = 1; d < 128; d <<= 1) {
        int x = (t >= d) ? sh[t - d] : 0;
        __syncthreads();
        if (t >= d) sh[t] += x;
        __syncthreads();
    }
    if (t < NB_SCAN) bsum[t] = sh[t] - v;
}

__global__ void scan3_k(int* __restrict__ off, int* __restrict__ pos,
                        const int* __restrict__ bsum) {
    int idx = blockIdx.x * blockDim.x + threadIdx.x;
    if (idx < N_NODES) {
        int o = off[idx] + bsum[idx >> 10];
        off[idx] = o;
        pos[idx] = o;
    }
}

__global__ void scat_k(const int* __restrict__ src, const int* __restrict__ dst,
                       int* __restrict__ pos, int* __restrict__ csrc) {
    int e = blockIdx.x * blockDim.x + threadIdx.x;
    if (e < N_EDGES) {
        int slot = atomicAdd(&pos[dst[e]], 1);
        csrc[slot] = src[e];
    }
}

// ---------------- CSR mean aggregation: one wave per node ----------------
__global__ void aggc_k(const u16* __restrict__ x, const int* __restrict__ off,
                       const int* __restrict__ pos, const int* __restrict__ csrc,
                       u16* __restrict__ mean) {
    int node = blockIdx.x * (blockDim.x >> 6) + (threadIdx.x >> 6);
    if (node >= N_NODES) return;
    int lane = threadIdx.x & 63;
    int s = off[node], e = pos[node];
    float acc[4] = {0.f, 0.f, 0.f, 0.f};
    for (int i = s; i < e; ++i) {
        int sr = csrc[i];
        uint2 u = *(const uint2*)(x + (size_t)sr * HID + lane * 4);
        acc[0] += bf2f(u.x & 0xffffu); acc[1] += bf2f(u.x >> 16);
        acc[2] += bf2f(u.y & 0xffffu); acc[3] += bf2f(u.y >> 16);
    }
    float inv = 1.0f / fmaxf((float)(e - s), 1.0f);
    uint2 r;
    r.x = pk2(acc[0] * inv, acc[1] * inv);
    r.y = pk2(acc[2] * inv, acc[3] * inv);
    *(uint2*)(mean + (size_t)node * HID + lane * 4) = r;
}

// ---------------- conversions ----------------
// x fp32 [100000][128] -> bf16
__global__ void cvt_x_k(const float* __restrict__ x, u16* __restrict__ xb) {
    int i = blockIdx.x * blockDim.x + threadIdx.x;   // 3.2M threads, 4 elems each
    float4 v = ((const float4*)x)[i];
    uint2 r; r.x = pk2(v.x, v.y); r.y = pk2(v.z, v.w);
    ((uint2*)xb)[i] = r;
}

// Bt[n][k] = bf16( k<K1 ? Wl[k][n] : Wr[k-K1][n] );  Ktot = 1<<LK
__global__ void wt_k(const float* __restrict__ Wl, const float* __restrict__ Wr,
                     u16* __restrict__ Bt, int K1, int LK, int N, int total) {
    int t = blockIdx.x * blockDim.x + threadIdx.x;
    if (t >= total) return;
    int n = t >> LK;
    int k = t & ((1 << LK) - 1);
    float v = (k < K1) ? Wl[(size_t)k * N + n] : Wr[(size_t)(k - K1) * N + n];
    Bt[t] = f2bf(v);
}

// ---------------- MFMA GEMM ----------------
// C[M][BN] = A[:, 0:64*SPLIT](from A1) ++ A[:, ...](from A2)  @  Bt^T   (+bias, epilogue)
// A1/A2: bf16, row stride ldaB bytes. Bt: bf16 [BN][KC*64] row-major.
// MODE 0: v=acc+bias; outb2=bf16(v), outb=bf16(relu(v)).
// MODE 1: v=relu(acc+bias)+0.2*inp; outb=bf16(v).
// MODE 2: v=acc+bias; outf[row*64+col]=v.
template<int KC, int SPLIT, int MODE, int BN, int THREADS>
__launch_bounds__(THREADS)
__global__ void mgemm_k(const u16* __restrict__ A1, const u16* __restrict__ A2,
                        int ldaB,
                        const u16* __restrict__ Bt,
                        const float* __restrict__ bias,
                        const u16* __restrict__ inp,
                        u16* __restrict__ outb, u16* __restrict__ outb2,
                        float* __restrict__ outf) {
    constexpr int W  = THREADS / 64;   // waves
    constexpr int WNW = W / 2;         // waves along N
    constexpr int WN  = BN / WNW;      // cols per wave
    constexpr int NFC = WN / 16;       // 16-col frags per wave
    constexpr int ASZ = 128 * 128;     // A tile bytes (128 rows x 128B)
    __shared__ char lds[ASZ + BN * 128];

    const int tid  = threadIdx.x;
    const int lane = tid & 63;
    const int wid  = tid >> 6;
    const int wr   = wid & 1;
    const int wc   = wid >> 1;
    const int r0   = blockIdx.x * 128;

    f32x4 acc[4][NFC];
    #pragma unroll
    for (int m = 0; m < 4; ++m)
        #pragma unroll
        for (int n = 0; n < NFC; ++n) acc[m][n] = (f32x4)(0.f);

    constexpr int AR = 128 / W, AI = AR / 8;   // A rows/wave, issues
    constexpr int BR = BN / W,  BI = BR / 8;   // B rows/wave, issues
    // pre-swizzled source slot (bytes): slot = (lane&7) ^ (row&7), row&7 == lane>>3
    const int sslot = (((lane & 7) ^ (lane >> 3)) << 4);
    const int lrow  = lane >> 3;

    for (int kc = 0; kc < KC; ++kc) {
        const u16* Ag = (kc < SPLIT) ? A1 : A2;
        const int  kb = ((kc < SPLIT) ? kc : kc - SPLIT) * 128;
        #pragma unroll
        for (int i = 0; i < AI; ++i) {
            const int rb = wid * AR + i * 8;
            int rg = r0 + rb + lrow;
            rg = (rg < N_NODES) ? rg : (N_NODES - 1);
            const char* g = (const char*)Ag + (size_t)rg * ldaB + kb + sslot;
            __builtin_amdgcn_global_load_lds(
                (__attribute__((address_space(1))) void*)g,
                (__attribute__((address_space(3))) void*)(lds + rb * 128),
                16, 0, 0);
        }
        #pragma unroll
        for (int i = 0; i < BI; ++i) {
            const int nb = wid * BR + i * 8;
            const int nt = nb + lrow;
            const char* g = (const char*)Bt + (size_t)nt * (KC * 128) + kc * 128 + sslot;
            __builtin_amdgcn_global_load_lds(
                (__attribute__((address_space(1))) void*)g,
                (__attribute__((address_space(3))) void*)(lds + ASZ + nb * 128),
                16, 0, 0);
        }
        __syncthreads();

        #pragma unroll
        for (int ks = 0; ks < 2; ++ks) {
            const int q = ((ks * 4 + (lane >> 4)) ^ (lane & 7)) << 4;
            short8 af[4], bv[NFC];
            #pragma unroll
            for (int m = 0; m < 4; ++m)
                af[m] = *(const short8*)(lds + (wr * 64 + m * 16 + (lane & 15)) * 128 + q);
            #pragma unroll
            for (int n = 0; n < NFC; ++n)
                bv[n] = *(const short8*)(lds + ASZ + (wc * WN + n * 16 + (lane & 15)) * 128 + q);
            #pragma unroll
            for (int m = 0; m < 4; ++m)
                #pragma unroll
                for (int n = 0; n < NFC; ++n)
                    acc[m][n] = __builtin_amdgcn_mfma_f32_16x16x32_bf16(
                        af[m], bv[n], acc[m][n], 0, 0, 0);
        }
        __syncthreads();
    }

    // ---- epilogue ----
    const int er = (lane >> 4) * 4;
    const int ec = lane & 15;
    #pragma unroll
    for (int m = 0; m < 4; ++m) {
        #pragma unroll
        for (int n = 0; n < NFC; ++n) {
            const int col = wc * WN + n * 16 + ec;
            const float bv = bias[col];
            f32x4 v = acc[m][n];
            #pragma unroll
            for (int r = 0; r < 4; ++r) {
                const int row = r0 + wr * 64 + m * 16 + er + r;
                if (row >= N_NODES) continue;
                float s = v[r] + bv;
                if constexpr (MODE == 0) {
                    outb2[(size_t)row * HID + col] = f2bf(s);
                    outb [(size_t)row * HID + col] = f2bf(fmaxf(s, 0.f));
                } else if constexpr (MODE == 1) {
                    float ip = bf2f(inp[(size_t)row * HID + col]);
                    outb[(size_t)row * HID + col] = f2bf(fmaxf(s, 0.f) + 0.2f * ip);
                } else {
                    outf[(size_t)row * 64 + col] = s;
                }
            }
        }
    }
}

// ---------------- in-place log_softmax over 64 cols, one wave per row ----------------
__global__ void lsm_k(float* __restrict__ out) {
    int r = blockIdx.x * 4 + (threadIdx.x >> 6);
    int lane = threadIdx.x & 63;
    if (r >= N_NODES) return;
    float v = out[(size_t)r * 64 + lane];
    float m = v;
    #pragma unroll
    for (int off = 32; off; off >>= 1) m = fmaxf(m, __shfl_xor(m, off));
    float s = expf(v - m);
    #pragma unroll
    for (int off = 32; off; off >>= 1) s += __shfl_xor(s, off);
    out[(size_t)r * 64 + lane] = (v - m) - logf(s);
}

extern "C" void kernel_launch(void* const* d_in, const int* in_sizes, int n_in,
                              void* d_out, int out_size, void* d_ws, size_t ws_size,
                              hipStream_t stream) {
    const float* x    = (const float*)d_in[0];
    const int*   ei   = (const int*)d_in[1];
    const float* W_in = (const float*)d_in[2];
    const float* b_in = (const float*)d_in[3];
    const float* Wl1  = (const float*)d_in[4];
    const float* bl1  = (const float*)d_in[5];
    const float* Wr1  = (const float*)d_in[6];
    const float* Wl2  = (const float*)d_in[7];
    const float* bl2  = (const float*)d_in[8];
    const float* Wr2  = (const float*)d_in[9];
    const float* Wl3  = (const float*)d_in[10];
    const float* bl3  = (const float*)d_in[11];
    const float* Wr3  = (const float*)d_in[12];
    float* out = (float*)d_out;

    const int* esrc = ei;
    const int* edst = ei + N_EDGES;

    char* ws = (char*)d_ws;
    u16* inp  = (u16*)(ws + 0);             // 51,200,000
    u16* xA   = (u16*)(ws + 51200000);      // 51,200,000
    u16* xB   = (u16*)(ws + 102400000);     // 51,200,000
    u16* mean = (u16*)(ws + 153600000);     // 51,200,000
    u16* xbf  = (u16*)(ws + 204800000);     // 25,600,000
    u16* BtIn = (u16*)(ws + 230400000);     // 65,536
    u16* Bt1  = (u16*)(ws + 230465536);     // 262,144
    u16* Bt2  = (u16*)(ws + 230727680);     // 262,144
    u16* Bt3  = (u16*)(ws + 230989824);     // 65,536
    int* icnt = (int*)(ws + 231055360);     // 400,000
    int* coff = (int*)(ws + 231455360);     // 400,000
    int* cpos = (int*)(ws + 231855360);     // 400,000
    int* csrc = (int*)(ws + 232255360);     // 1,200,000
    int* bsum = (int*)(ws + 233455360);     // 512

    dim3 blk(256);
    dim3 gE((N_EDGES + 255) / 256);
    dim3 gN((N_NODES + 255) / 256);
    dim3 gAgg((N_NODES + 3) / 4);
    dim3 gG((N_NODES + 127) / 128);         // 782

    // ---- CSR build ----
    hipMemsetAsync(icnt, 0, (size_t)N_NODES * 4, stream);
    icnt_k<<<gE, blk, 0, stream>>>(edst, icnt);
    scan1_k<<<NB_SCAN, blk, 0, stream>>>(icnt, coff, bsum);
    scan2_k<<<1, 128, 0, stream>>>(bsum);
    scan3_k<<<gN, blk, 0, stream>>>(coff, cpos, bsum);
    scat_k<<<gE, blk, 0, stream>>>(esrc, edst, cpos, csrc);

    // ---- conversions ----
    cvt_x_k<<<(N_NODES * 128 / 4 + 255) / 256, blk, 0, stream>>>(x, xbf);
    wt_k<<<(256 * 128 + 255) / 256, blk, 0, stream>>>(W_in, W_in, BtIn, 128, 7, 256, 256 * 128);
    wt_k<<<(256 * 512 + 255) / 256, blk, 0, stream>>>(Wl1, Wr1, Bt1, 256, 9, 256, 256 * 512);
    wt_k<<<(256 * 512 + 255) / 256, blk, 0, stream>>>(Wl2, Wr2, Bt2, 256, 9, 256, 256 * 512);
    wt_k<<<(64 * 512 + 255) / 256, blk, 0, stream>>>(Wl3, Wr3, Bt3, 256, 9, 64, 64 * 512);

    // ---- input: H0 = x @ W_in + b_in ; inp = H0, xA = relu(H0) ----
    mgemm_k<2, 2, 0, 256, 512><<<gG, 512, 0, stream>>>(
        xbf, xbf, 256, BtIn, b_in, nullptr, xA, inp, nullptr);

    // ---- layer 1 ----
    aggc_k<<<gAgg, blk, 0, stream>>>(xA, coff, cpos, csrc, mean);
    mgemm_k<8, 4, 1, 256, 512><<<gG, 512, 0, stream>>>(
        mean, xA, 512, Bt1, bl1, inp, xB, nullptr, nullptr);

    // ---- layer 2 ----
    aggc_k<<<gAgg, blk, 0, stream>>>(xB, coff, cpos, csrc, mean);
    mgemm_k<8, 4, 1, 256, 512><<<gG, 512, 0, stream>>>(
        mean, xB, 512, Bt2, bl2, inp, xA, nullptr, nullptr);

    // ---- layer 3 ----
    aggc_k<<<gAgg, blk, 0, stream>>>(xA, coff, cpos, csrc, mean);
    mgemm_k<8, 4, 2, 64, 256><<<gG, blk, 0, stream>>>(
        mean, xA, 512, Bt3, bl3, nullptr, nullptr, nullptr, out);

    // ---- log_softmax in place ----
    lsm_k<<<N_NODES / 4, blk, 0, stream>>>(out);
}

// Round 4
// 383.785 us; speedup vs baseline: 19.6991x; 1.0707x over previous
//
#include <hip/hip_runtime.h>
#include <hip/hip_bf16.h>
#include <stdint.h>

#define N_NODES 100000
#define N_EDGES 300000
#define HID 256
#define NB_SCAN 98   // ceil(100000/1024)

typedef unsigned short u16;
typedef unsigned int u32;
typedef __attribute__((ext_vector_type(8))) short short8;
typedef __attribute__((ext_vector_type(4))) float f32x4;

__device__ __forceinline__ float bf2f(u16 u) {
    union { u32 i; float f; } c; c.i = ((u32)u) << 16; return c.f;
}
__device__ __forceinline__ u16 f2bf(float f) {
    union { float f; u32 i; } c; c.f = f;
    u32 x = c.i;
    u32 r = (x + 0x7fffu + ((x >> 16) & 1u)) >> 16;  // round-nearest-even
    return (u16)r;
}
__device__ __forceinline__ u32 pk2(float lo, float hi) {
    return (u32)f2bf(lo) | ((u32)f2bf(hi) << 16);
}
__device__ __forceinline__ void unpack8(uint4 u, float* f) {
    f[0] = bf2f(u.x & 0xffffu); f[1] = bf2f(u.x >> 16);
    f[2] = bf2f(u.y & 0xffffu); f[3] = bf2f(u.y >> 16);
    f[4] = bf2f(u.z & 0xffffu); f[5] = bf2f(u.z >> 16);
    f[6] = bf2f(u.w & 0xffffu); f[7] = bf2f(u.w >> 16);
}

// ---------------- CSR build ----------------
__global__ void icnt_k(const int* __restrict__ dst, int* __restrict__ icnt) {
    int e = blockIdx.x * blockDim.x + threadIdx.x;
    if (e < N_EDGES) atomicAdd(&icnt[dst[e]], 1);
}

__global__ void scan1_k(const int* __restrict__ icnt, int* __restrict__ off,
                        int* __restrict__ bsum) {
    __shared__ int sh[256];
    int t = threadIdx.x;
    int base = blockIdx.x * 1024 + t * 4;
    int v[4];
    #pragma unroll
    for (int j = 0; j < 4; ++j) {
        int idx = base + j;
        v[j] = (idx < N_NODES) ? icnt[idx] : 0;
    }
    int s = v[0] + v[1] + v[2] + v[3];
    sh[t] = s;
    __syncthreads();
    #pragma unroll
    for (int d = 1; d < 256; d <<= 1) {
        int x = (t >= d) ? sh[t - d] : 0;
        __syncthreads();
        if (t >= d) sh[t] += x;
        __syncthreads();
    }
    int excl = sh[t] - s;
    #pragma unroll
    for (int j = 0; j < 4; ++j) {
        int idx = base + j;
        if (idx < N_NODES) off[idx] = excl;
        excl += v[j];
    }
    if (t == 255) bsum[blockIdx.x] = sh[255];
}

__global__ void scan2_k(int* __restrict__ bsum) {
    __shared__ int sh[128];
    int t = threadIdx.x;
    int v = (t < NB_SCAN) ? bsum[t] : 0;
    sh[t] = v;
    __syncthreads();
    #pragma unroll
    for (int d = 1; d < 128; d <<= 1) {
        int x = (t >= d) ? sh[t - d] : 0;
        __syncthreads();
        if (t >= d) sh[t] += x;
        __syncthreads();
    }
    if (t < NB_SCAN) bsum[t] = sh[t] - v;
}

__global__ void scan3_k(int* __restrict__ off, int* __restrict__ pos,
                        const int* __restrict__ bsum) {
    int idx = blockIdx.x * blockDim.x + threadIdx.x;
    if (idx < N_NODES) {
        int o = off[idx] + bsum[idx >> 10];
        off[idx] = o;
        pos[idx] = o;
    }
}

__global__ void scat_k(const int* __restrict__ src, const int* __restrict__ dst,
                       int* __restrict__ pos, int* __restrict__ csrc) {
    int e = blockIdx.x * blockDim.x + threadIdx.x;
    if (e < N_EDGES) {
        int slot = atomicAdd(&pos[dst[e]], 1);
        csrc[slot] = src[e];
    }
}

// ---------------- CSR mean aggregation: 32 lanes per node ----------------
__global__ void aggc_k(const u16* __restrict__ x, const int* __restrict__ off,
                       const int* __restrict__ pos, const int* __restrict__ csrc,
                       u16* __restrict__ mean) {
    int node = blockIdx.x * (blockDim.x >> 5) + (threadIdx.x >> 5);
    if (node >= N_NODES) return;
    int lane = threadIdx.x & 31;
    int s = off[node], e = pos[node];
    float acc[8] = {0.f, 0.f, 0.f, 0.f, 0.f, 0.f, 0.f, 0.f};
    for (int i = s; i < e; ++i) {
        int sr = csrc[i];
        uint4 u = *(const uint4*)(x + (size_t)sr * HID + lane * 8);
        float f[8];
        unpack8(u, f);
        #pragma unroll
        for (int j = 0; j < 8; ++j) acc[j] += f[j];
    }
    float inv = 1.0f / fmaxf((float)(e - s), 1.0f);
    uint4 r;
    r.x = pk2(acc[0] * inv, acc[1] * inv);
    r.y = pk2(acc[2] * inv, acc[3] * inv);
    r.z = pk2(acc[4] * inv, acc[5] * inv);
    r.w = pk2(acc[6] * inv, acc[7] * inv);
    *(uint4*)(mean + (size_t)node * HID + lane * 8) = r;
}

// ---------------- conversions ----------------
__global__ void cvt_x_k(const float* __restrict__ x, u16* __restrict__ xb) {
    int i = blockIdx.x * blockDim.x + threadIdx.x;
    float4 v = ((const float4*)x)[i];
    uint2 r; r.x = pk2(v.x, v.y); r.y = pk2(v.z, v.w);
    ((uint2*)xb)[i] = r;
}

__global__ void wt_k(const float* __restrict__ Wl, const float* __restrict__ Wr,
                     u16* __restrict__ Bt, int K1, int LK, int N, int total) {
    int t = blockIdx.x * blockDim.x + threadIdx.x;
    if (t >= total) return;
    int n = t >> LK;
    int k = t & ((1 << LK) - 1);
    float v = (k < K1) ? Wl[(size_t)k * N + n] : Wr[(size_t)(k - K1) * N + n];
    Bt[t] = f2bf(v);
}

// ---------------- MFMA GEMM, 2-phase pipelined (counted vmcnt) ----------------
// A double-buffered (2x16KB), B single-buffered (BN*128B). Per K-step:
//   issue B(kc), issue A(kc+1)->alt buf, s_waitcnt vmcnt(AI) [A(kc+1) stays
//   in flight across the barrier], s_barrier, ds_read+MFMA, s_barrier.
template<int KC, int SPLIT, int MODE, int BN, int THREADS>
__launch_bounds__(THREADS)
__global__ void mgemm_k(const u16* __restrict__ A1, const u16* __restrict__ A2,
                        int ldaB,
                        const u16* __restrict__ Bt,
                        const float* __restrict__ bias,
                        const u16* __restrict__ inp,
                        u16* __restrict__ outb, u16* __restrict__ outb2,
                        float* __restrict__ outf) {
    constexpr int W   = THREADS / 64;
    constexpr int WNW = W / 2;
    constexpr int WN  = BN / WNW;
    constexpr int NFC = WN / 16;
    constexpr int ABYTES = 128 * 128;       // one A buffer
    constexpr int AR = 128 / W, AI = AR / 8;
    constexpr int BR = BN / W,  BI = BR / 8;
    __shared__ char lds[2 * ABYTES + BN * 128];

    const int tid  = threadIdx.x;
    const int lane = tid & 63;
    const int wid  = tid >> 6;
    const int wr   = wid & 1;
    const int wc   = wid >> 1;
    const int r0   = blockIdx.x * 128;

    f32x4 acc[4][NFC];
    #pragma unroll
    for (int m = 0; m < 4; ++m)
        #pragma unroll
        for (int n = 0; n < NFC; ++n) acc[m][n] = (f32x4)(0.f);

    // pre-swizzled source slot: slot = (lane&7) ^ (row&7); row&7 == lane>>3
    const int sslot = (((lane & 7) ^ (lane >> 3)) << 4);
    const int lrow  = lane >> 3;

    auto stage_a = [&](int kc, int buf) {
        const u16* Ag = (kc < SPLIT) ? A1 : A2;
        const int  kb = ((kc < SPLIT) ? kc : kc - SPLIT) * 128;
        #pragma unroll
        for (int i = 0; i < AI; ++i) {
            const int rb = wid * AR + i * 8;
            int rg = r0 + rb + lrow;
            rg = (rg < N_NODES) ? rg : (N_NODES - 1);
            const char* g = (const char*)Ag + (size_t)rg * ldaB + kb + sslot;
            __builtin_amdgcn_global_load_lds(
                (__attribute__((address_space(1))) void*)g,
                (__attribute__((address_space(3))) void*)(lds + buf * ABYTES + rb * 128),
                16, 0, 0);
        }
    };
    auto stage_b = [&](int kc) {
        #pragma unroll
        for (int i = 0; i < BI; ++i) {
            const int nb = wid * BR + i * 8;
            const int nt = nb + lrow;
            const char* g = (const char*)Bt + (size_t)nt * (KC * 128) + kc * 128 + sslot;
            __builtin_amdgcn_global_load_lds(
                (__attribute__((address_space(1))) void*)g,
                (__attribute__((address_space(3))) void*)(lds + 2 * ABYTES + nb * 128),
                16, 0, 0);
        }
    };

    stage_a(0, 0);
    int cur = 0;
    for (int kc = 0; kc < KC; ++kc) {
        stage_b(kc);
        if (kc + 1 < KC) {
            stage_a(kc + 1, cur ^ 1);
            asm volatile("s_waitcnt vmcnt(%0)" :: "i"(AI) : "memory");
        } else {
            asm volatile("s_waitcnt vmcnt(0)" ::: "memory");
        }
        __builtin_amdgcn_s_barrier();
        __builtin_amdgcn_sched_barrier(0);

        const char* Ab = lds + cur * ABYTES;
        const char* Bb = lds + 2 * ABYTES;
        #pragma unroll
        for (int ks = 0; ks < 2; ++ks) {
            const int q = ((ks * 4 + (lane >> 4)) ^ (lane & 7)) << 4;
            short8 af[4], bv[NFC];
            #pragma unroll
            for (int m = 0; m < 4; ++m)
                af[m] = *(const short8*)(Ab + (wr * 64 + m * 16 + (lane & 15)) * 128 + q);
            #pragma unroll
            for (int n = 0; n < NFC; ++n)
                bv[n] = *(const short8*)(Bb + (wc * WN + n * 16 + (lane & 15)) * 128 + q);
            #pragma unroll
            for (int m = 0; m < 4; ++m)
                #pragma unroll
                for (int n = 0; n < NFC; ++n)
                    acc[m][n] = __builtin_amdgcn_mfma_f32_16x16x32_bf16(
                        af[m], bv[n], acc[m][n], 0, 0, 0);
        }
        asm volatile("" ::: "memory");
        __builtin_amdgcn_s_barrier();
        cur ^= 1;
    }

    // ---- epilogue ----
    const int er = (lane >> 4) * 4;
    const int ec = lane & 15;
    #pragma unroll
    for (int m = 0; m < 4; ++m) {
        #pragma unroll
        for (int n = 0; n < NFC; ++n) {
            const int col = wc * WN + n * 16 + ec;
            const float bv = bias[col];
            f32x4 v = acc[m][n];
            #pragma unroll
            for (int r = 0; r < 4; ++r) {
                const int row = r0 + wr * 64 + m * 16 + er + r;
                if (row >= N_NODES) continue;
                float s = v[r] + bv;
                if constexpr (MODE == 0) {
                    outb2[(size_t)row * HID + col] = f2bf(s);
                    outb [(size_t)row * HID + col] = f2bf(fmaxf(s, 0.f));
                } else if constexpr (MODE == 1) {
                    float ip = bf2f(inp[(size_t)row * HID + col]);
                    outb[(size_t)row * HID + col] = f2bf(fmaxf(s, 0.f) + 0.2f * ip);
                } else {
                    outf[(size_t)row * 64 + col] = s;
                }
            }
        }
    }
}

// ---------------- in-place log_softmax over 64 cols, one wave per row ----------------
__global__ void lsm_k(float* __restrict__ out) {
    int r = blockIdx.x * 4 + (threadIdx.x >> 6);
    int lane = threadIdx.x & 63;
    if (r >= N_NODES) return;
    float v = out[(size_t)r * 64 + lane];
    float m = v;
    #pragma unroll
    for (int off = 32; off; off >>= 1) m = fmaxf(m, __shfl_xor(m, off));
    float s = expf(v - m);
    #pragma unroll
    for (int off = 32; off; off >>= 1) s += __shfl_xor(s, off);
    out[(size_t)r * 64 + lane] = (v - m) - logf(s);
}

extern "C" void kernel_launch(void* const* d_in, const int* in_sizes, int n_in,
                              void* d_out, int out_size, void* d_ws, size_t ws_size,
                              hipStream_t stream) {
    const float* x    = (const float*)d_in[0];
    const int*   ei   = (const int*)d_in[1];
    const float* W_in = (const float*)d_in[2];
    const float* b_in = (const float*)d_in[3];
    const float* Wl1  = (const float*)d_in[4];
    const float* bl1  = (const float*)d_in[5];
    const float* Wr1  = (const float*)d_in[6];
    const float* Wl2  = (const float*)d_in[7];
    const float* bl2  = (const float*)d_in[8];
    const float* Wr2  = (const float*)d_in[9];
    const float* Wl3  = (const float*)d_in[10];
    const float* bl3  = (const float*)d_in[11];
    const float* Wr3  = (const float*)d_in[12];
    float* out = (float*)d_out;

    const int* esrc = ei;
    const int* edst = ei + N_EDGES;

    char* ws = (char*)d_ws;
    u16* inp  = (u16*)(ws + 0);             // 51,200,000
    u16* xA   = (u16*)(ws + 51200000);      // 51,200,000
    u16* xB   = (u16*)(ws + 102400000);     // 51,200,000
    u16* mean = (u16*)(ws + 153600000);     // 51,200,000
    u16* xbf  = (u16*)(ws + 204800000);     // 25,600,000
    u16* BtIn = (u16*)(ws + 230400000);     // 65,536
    u16* Bt1  = (u16*)(ws + 230465536);     // 262,144
    u16* Bt2  = (u16*)(ws + 230727680);     // 262,144
    u16* Bt3  = (u16*)(ws + 230989824);     // 65,536
    int* icnt = (int*)(ws + 231055360);     // 400,000
    int* coff = (int*)(ws + 231455360);     // 400,000
    int* cpos = (int*)(ws + 231855360);     // 400,000
    int* csrc = (int*)(ws + 232255360);     // 1,200,000
    int* bsum = (int*)(ws + 233455360);     // 512

    dim3 blk(256);
    dim3 gE((N_EDGES + 255) / 256);
    dim3 gN((N_NODES + 255) / 256);
    dim3 gAgg((N_NODES + 7) / 8);
    dim3 gG((N_NODES + 127) / 128);         // 782

    // ---- CSR build ----
    hipMemsetAsync(icnt, 0, (size_t)N_NODES * 4, stream);
    icnt_k<<<gE, blk, 0, stream>>>(edst, icnt);
    scan1_k<<<NB_SCAN, blk, 0, stream>>>(icnt, coff, bsum);
    scan2_k<<<1, 128, 0, stream>>>(bsum);
    scan3_k<<<gN, blk, 0, stream>>>(coff, cpos, bsum);
    scat_k<<<gE, blk, 0, stream>>>(esrc, edst, cpos, csrc);

    // ---- conversions ----
    cvt_x_k<<<(N_NODES * 128 / 4 + 255) / 256, blk, 0, stream>>>(x, xbf);
    wt_k<<<(256 * 128 + 255) / 256, blk, 0, stream>>>(W_in, W_in, BtIn, 128, 7, 256, 256 * 128);
    wt_k<<<(256 * 512 + 255) / 256, blk, 0, stream>>>(Wl1, Wr1, Bt1, 256, 9, 256, 256 * 512);
    wt_k<<<(256 * 512 + 255) / 256, blk, 0, stream>>>(Wl2, Wr2, Bt2, 256, 9, 256, 256 * 512);
    wt_k<<<(64 * 512 + 255) / 256, blk, 0, stream>>>(Wl3, Wr3, Bt3, 256, 9, 64, 64 * 512);

    // ---- input: H0 = x @ W_in + b_in ; inp = H0, xA = relu(H0) ----
    mgemm_k<2, 2, 0, 256, 512><<<gG, 512, 0, stream>>>(
        xbf, xbf, 256, BtIn, b_in, nullptr, xA, inp, nullptr);

    // ---- layer 1 ----
    aggc_k<<<gAgg, blk, 0, stream>>>(xA, coff, cpos, csrc, mean);
    mgemm_k<8, 4, 1, 256, 512><<<gG, 512, 0, stream>>>(
        mean, xA, 512, Bt1, bl1, inp, xB, nullptr, nullptr);

    // ---- layer 2 ----
    aggc_k<<<gAgg, blk, 0, stream>>>(xB, coff, cpos, csrc, mean);
    mgemm_k<8, 4, 1, 256, 512><<<gG, 512, 0, stream>>>(
        mean, xB, Bt2 ? 512 : 512, Bt2, bl2, inp, xA, nullptr, nullptr);

    // ---- layer 3 ----
    aggc_k<<<gAgg, blk, 0, stream>>>(xA, coff, cpos, csrc, mean);
    mgemm_k<8, 4, 2, 64, 256><<<gG, blk, 0, stream>>>(
        mean, xA, 512, Bt3, bl3, nullptr, nullptr, nullptr, out);

    // ---- log_softmax in place ----
    lsm_k<<<N_NODES / 4, blk, 0, stream>>>(out);
}